// Round 2
// baseline (613.997 us; speedup 1.0000x reference)
//
#include <hip/hip_runtime.h>
#include <hip/hip_bf16.h>
#include <math.h>

#define N_NODES 100000
#define N_EDGES 1000000
#define DIM 64

typedef __hip_bfloat16 bf16;

__device__ __forceinline__ float b2f(bf16 v) { return __bfloat162float(v); }

__device__ __forceinline__ void atomAddF(float* p, float v) {
    // d_ws is hipMalloc'd (coarse-grained) -> native global_atomic_add_f32
    unsafeAtomicAdd(p, v);
}

// Flag-branched float load: isb!=0 -> buffer holds bf16, else fp32.
__device__ __forceinline__ float loadF(const void* p, long i, int isb) {
    return isb ? b2f(((const bf16*)p)[i]) : ((const float*)p)[i];
}

__device__ __forceinline__ int clampN(int v) {
    return v < 0 ? 0 : (v >= N_NODES ? N_NODES - 1 : v);
}

// ---------------------------------------------------------------------------
// Kernel 0: detect on-device encodings.
//   flags[0] = 1 if float arrays are bf16-packed, 0 if fp32.
//   flags[1] = 1 if edge_index is int64 (read as int32 pairs), 0 if int32.
// Data-driven, identical every call (graph-safe).
// ---------------------------------------------------------------------------
__global__ void detect_kernel(const void* xraw, const int* ei, int* flags) {
    __shared__ int cnt_small, cnt_odd_nz;
    if (threadIdx.x == 0) { cnt_small = 0; cnt_odd_nz = 0; }
    __syncthreads();
    const float* xf = (const float*)xraw;
    int ls = 0;
    for (int i = threadIdx.x; i < 4096; i += 256) {
        float v = xf[i];                       // in-bounds under either dtype
        if (v == v && fabsf(v) < 100.0f) ls++; // fp32 N(0,1): true; bf16-pair: ~never
    }
    atomicAdd(&cnt_small, ls);
    int lo = 0;
    for (int i = threadIdx.x; i < 2048; i += 256) {
        if (ei[2 * i + 1] != 0) lo++;          // int64 high words are all zero
    }
    atomicAdd(&cnt_odd_nz, lo);
    __syncthreads();
    if (threadIdx.x == 0) {
        flags[0] = (cnt_small < 2048) ? 1 : 0;
        flags[1] = (cnt_odd_nz == 0) ? 1 : 0;
    }
}

// ---------------------------------------------------------------------------
// Kernel 1: per-edge scatter of raw x into fp32 sum buffer + degree.
// One wave per edge: lane d handles feature dim d.
// ---------------------------------------------------------------------------
__global__ void scatter_x_kernel(const void* __restrict__ x,
                                 const int* __restrict__ ei,
                                 float* __restrict__ agg,
                                 float* __restrict__ deg,
                                 const int* __restrict__ flags) {
    const int isb = flags[0];
    const int sh  = flags[1];                 // 0: int32, 1: int64 (stride 2)
    const long dstbase = (long)N_EDGES << sh;
    int lane = threadIdx.x & 63;
    int wave = blockIdx.x * (blockDim.x >> 6) + (threadIdx.x >> 6);
    int nwaves = gridDim.x * (blockDim.x >> 6);
    for (int e = wave; e < N_EDGES; e += nwaves) {
        int src = clampN(ei[(long)e << sh]);
        int dst = clampN(ei[dstbase + ((long)e << sh)]);
        float v = loadF(x, (long)src * DIM + lane, isb);
        atomAddF(&agg[(long)dst * DIM + lane], v);
        if (lane == 0) atomAddF(&deg[dst], 1.0f);
    }
}

// ---------------------------------------------------------------------------
// Kernel 2: fused layer-0 + layer-1 head per node.
//   mean = agg[n]/max(deg,1); h = relu(mean@Wl0^T + x[n]@Wr0^T + bl0)
//   s[n] = h . Wl1 ; t[n] = h . Wr1
// One wave per node; lane d owns output dim d. Transposed weights in LDS,
// stride 65 (bank-conflict-free); rows broadcast via __shfl.
// ---------------------------------------------------------------------------
__global__ void layer_fused_kernel(const void* __restrict__ x,
                                   const void* __restrict__ Wl0,
                                   const void* __restrict__ bl0,
                                   const void* __restrict__ Wr0,
                                   const void* __restrict__ Wl1,
                                   const void* __restrict__ Wr1,
                                   const float* __restrict__ agg,
                                   const float* __restrict__ deg,
                                   float* __restrict__ s,
                                   float* __restrict__ t,
                                   const int* __restrict__ flags) {
    __shared__ float WTl[64 * 65];   // WTl[k*65+d] = Wl0[d][k]
    __shared__ float WTr[64 * 65];
    __shared__ float sWl1[64], sWr1[64], sb0[64];
    const int isb = flags[0];

    for (int i = threadIdx.x; i < 4096; i += blockDim.x) {
        int d = i >> 6, k = i & 63;
        WTl[k * 65 + d] = loadF(Wl0, i, isb);
        WTr[k * 65 + d] = loadF(Wr0, i, isb);
    }
    if (threadIdx.x < 64) {
        sWl1[threadIdx.x] = loadF(Wl1, threadIdx.x, isb);
        sWr1[threadIdx.x] = loadF(Wr1, threadIdx.x, isb);
        sb0[threadIdx.x]  = loadF(bl0, threadIdx.x, isb);
    }
    __syncthreads();

    int lane = threadIdx.x & 63;
    int wave = blockIdx.x * (blockDim.x >> 6) + (threadIdx.x >> 6);
    int nwaves = gridDim.x * (blockDim.x >> 6);

    for (int n = wave; n < N_NODES; n += nwaves) {
        float xv = loadF(x, (long)n * DIM + lane, isb);
        float dg = fmaxf(deg[n], 1.0f);
        float mv = agg[(long)n * DIM + lane] / dg;

        float acc = sb0[lane];
        #pragma unroll
        for (int k = 0; k < 64; ++k) {
            acc = fmaf(__shfl(mv, k, 64), WTl[k * 65 + lane], acc);
            acc = fmaf(__shfl(xv, k, 64), WTr[k * 65 + lane], acc);
        }
        float h = fmaxf(acc, 0.0f);

        float vs = h * sWl1[lane];
        float vt = h * sWr1[lane];
        #pragma unroll
        for (int off = 32; off; off >>= 1) {
            vs += __shfl_xor(vs, off, 64);
            vt += __shfl_xor(vt, off, 64);
        }
        if (lane == 0) { s[n] = vs; t[n] = vt; }
    }
}

// ---------------------------------------------------------------------------
// Kernel 3: scalar per-edge scatter of s into aggs.
// ---------------------------------------------------------------------------
__global__ void scatter_s_kernel(const float* __restrict__ s,
                                 const int* __restrict__ ei,
                                 float* __restrict__ aggs,
                                 const int* __restrict__ flags) {
    const int sh = flags[1];
    const long dstbase = (long)N_EDGES << sh;
    int tid = blockIdx.x * blockDim.x + threadIdx.x;
    int nthreads = gridDim.x * blockDim.x;
    for (int e = tid; e < N_EDGES; e += nthreads) {
        int src = clampN(ei[(long)e << sh]);
        int dst = clampN(ei[dstbase + ((long)e << sh)]);
        atomAddF(&aggs[dst], s[src]);
    }
}

// ---------------------------------------------------------------------------
// Kernel 4: final per-node output: v = aggs/deg + bl1 + t ; out = (v, sigmoid)
// Output dtype follows the detected float mode.
// ---------------------------------------------------------------------------
__global__ void final_kernel(const float* __restrict__ aggs,
                             const float* __restrict__ deg,
                             const float* __restrict__ t,
                             const void* __restrict__ bl1,
                             void* __restrict__ out,
                             const int* __restrict__ flags) {
    const int isb = flags[0];
    int n = blockIdx.x * blockDim.x + threadIdx.x;
    if (n < N_NODES) {
        float dg = fmaxf(deg[n], 1.0f);
        float v = aggs[n] / dg + loadF(bl1, 0, isb) + t[n];
        float sg = 1.0f / (1.0f + expf(-v));
        if (isb) {
            ((bf16*)out)[n] = __float2bfloat16(v);
            ((bf16*)out)[N_NODES + n] = __float2bfloat16(sg);
        } else {
            ((float*)out)[n] = v;
            ((float*)out)[N_NODES + n] = sg;
        }
    }
}

extern "C" void kernel_launch(void* const* d_in, const int* in_sizes, int n_in,
                              void* d_out, int out_size, void* d_ws, size_t ws_size,
                              hipStream_t stream) {
    const void* x   = d_in[0];
    const int*  ei  = (const int*)d_in[1];   // [2, E]; width auto-detected
    const void* Wl0 = d_in[2];
    const void* bl0 = d_in[3];
    const void* Wr0 = d_in[4];
    const void* Wl1 = d_in[5];
    const void* bl1 = d_in[6];
    const void* Wr1 = d_in[7];

    // Workspace layout (27.2 MB total):
    //   flags @ 0        (256 B)
    //   deg   @ 256      (400,000 B)
    //   aggs  @ 400,256  (400,000 B)
    //   s     @ 800,256  (400,000 B)
    //   t     @ 1,200,256(400,000 B)
    //   agg   @ 1,600,256(25,600,000 B)
    char* ws = (char*)d_ws;
    int*   flags = (int*)(ws);
    float* deg   = (float*)(ws + 256);
    float* aggs  = (float*)(ws + 400256);
    float* s     = (float*)(ws + 800256);
    float* t     = (float*)(ws + 1200256);
    float* agg   = (float*)(ws + 1600256);

    hipMemsetAsync(ws, 0, 27200256, stream);

    detect_kernel<<<1, 256, 0, stream>>>(x, ei, flags);
    scatter_x_kernel<<<4096, 256, 0, stream>>>(x, ei, agg, deg, flags);
    layer_fused_kernel<<<1024, 256, 0, stream>>>(x, Wl0, bl0, Wr0, Wl1, Wr1,
                                                 agg, deg, s, t, flags);
    scatter_s_kernel<<<2048, 256, 0, stream>>>(s, ei, aggs, flags);
    final_kernel<<<(N_NODES + 255) / 256, 256, 0, stream>>>(aggs, deg, t, bl1,
                                                            out_size ? d_out : d_out, flags);
}

// Round 3
// 382.741 us; speedup vs baseline: 1.6042x; 1.6042x over previous
//
#include <hip/hip_runtime.h>
#include <hip/hip_bf16.h>
#include <math.h>

#define N_NODES 100000
#define N_EDGES 1000000
#define DIM 64
#define SCAN_BLOCKS 391   // ceil(N_NODES/256)

typedef __hip_bfloat16 bf16;

__device__ __forceinline__ float b2f(bf16 v) { return __bfloat162float(v); }

// Flag-branched float load: isb!=0 -> buffer holds bf16, else fp32.
__device__ __forceinline__ float loadF(const void* p, long i, int isb) {
    return isb ? b2f(((const bf16*)p)[i]) : ((const float*)p)[i];
}

__device__ __forceinline__ int clampN(int v) {
    return v < 0 ? 0 : (v >= N_NODES ? N_NODES - 1 : v);
}

// ---------------------------------------------------------------------------
// Kernel 0: detect on-device encodings (graph-safe, data-driven).
//   flags[0]=1 if floats are bf16-packed; flags[1]=1 if edge_index is int64.
// ---------------------------------------------------------------------------
__global__ void detect_kernel(const void* xraw, const int* ei, int* flags) {
    __shared__ int cnt_small, cnt_odd_nz;
    if (threadIdx.x == 0) { cnt_small = 0; cnt_odd_nz = 0; }
    __syncthreads();
    const float* xf = (const float*)xraw;
    int ls = 0;
    for (int i = threadIdx.x; i < 4096; i += 256) {
        float v = xf[i];
        if (v == v && fabsf(v) < 100.0f) ls++;
    }
    atomicAdd(&cnt_small, ls);
    int lo = 0;
    for (int i = threadIdx.x; i < 2048; i += 256) {
        if (ei[2 * i + 1] != 0) lo++;
    }
    atomicAdd(&cnt_odd_nz, lo);
    __syncthreads();
    if (threadIdx.x == 0) {
        flags[0] = (cnt_small < 2048) ? 1 : 0;
        flags[1] = (cnt_odd_nz == 0) ? 1 : 0;
    }
}

// ---------------------------------------------------------------------------
// CSR build: histogram -> scan (3 kernels) -> fill
// ---------------------------------------------------------------------------
__global__ void hist_kernel(const int* __restrict__ ei, int* __restrict__ degi,
                            const int* __restrict__ flags) {
    const int sh = flags[1];
    const long dstbase = (long)N_EDGES << sh;
    int e = blockIdx.x * blockDim.x + threadIdx.x;
    if (e < N_EDGES) {
        int dst = clampN(ei[dstbase + ((long)e << sh)]);
        atomicAdd(&degi[dst], 1);
    }
}

__global__ void scan1_kernel(const int* __restrict__ degi,
                             int* __restrict__ rowstart, int* __restrict__ bsum) {
    __shared__ int sc[256];
    int t = threadIdx.x;
    int i = blockIdx.x * 256 + t;
    int v = (i < N_NODES) ? degi[i] : 0;
    sc[t] = v;
    __syncthreads();
    #pragma unroll
    for (int off = 1; off < 256; off <<= 1) {
        int u = (t >= off) ? sc[t - off] : 0;
        __syncthreads();
        sc[t] += u;
        __syncthreads();
    }
    if (i < N_NODES) rowstart[i] = sc[t] - v;   // exclusive
    if (t == 255) bsum[blockIdx.x] = sc[t];
}

__global__ void scan2_kernel(int* __restrict__ bsum) {
    __shared__ int sc[512];
    int t = threadIdx.x;
    int v = (t < SCAN_BLOCKS) ? bsum[t] : 0;
    sc[t] = v;
    __syncthreads();
    #pragma unroll
    for (int off = 1; off < 512; off <<= 1) {
        int u = (t >= off) ? sc[t - off] : 0;
        __syncthreads();
        sc[t] += u;
        __syncthreads();
    }
    if (t < SCAN_BLOCKS) bsum[t] = sc[t] - v;   // exclusive
}

__global__ void scan3_kernel(int* __restrict__ rowstart, const int* __restrict__ bsum) {
    int i = blockIdx.x * 256 + threadIdx.x;
    if (i < N_NODES) rowstart[i] += bsum[blockIdx.x];
}

__global__ void fill_kernel(const int* __restrict__ ei,
                            const int* __restrict__ rowstart,
                            int* __restrict__ cursor, int* __restrict__ csr,
                            const int* __restrict__ flags) {
    const int sh = flags[1];
    const long dstbase = (long)N_EDGES << sh;
    int e = blockIdx.x * blockDim.x + threadIdx.x;
    if (e < N_EDGES) {
        int src = clampN(ei[(long)e << sh]);
        int dst = clampN(ei[dstbase + ((long)e << sh)]);
        int pos = atomicAdd(&cursor[dst], 1);
        csr[rowstart[dst] + pos] = src;
    }
}

// ---------------------------------------------------------------------------
// Aggregate: one wave per node; lane d sums x[src][d] over in-edges, writes
// mean as bf16 (12.8 MB).
// ---------------------------------------------------------------------------
__global__ void aggregate_kernel(const void* __restrict__ x,
                                 const int* __restrict__ rowstart,
                                 const int* __restrict__ degi,
                                 const int* __restrict__ csr,
                                 bf16* __restrict__ meanb,
                                 const int* __restrict__ flags) {
    const int isb = flags[0];
    int lane = threadIdx.x & 63;
    int n = blockIdx.x * (blockDim.x >> 6) + (threadIdx.x >> 6);
    if (n >= N_NODES) return;
    int beg = rowstart[n], cnt = degi[n];
    float acc = 0.0f;
    for (int i = 0; i < cnt; ++i) {
        int src = csr[beg + i];
        acc += loadF(x, (long)src * DIM + lane, isb);
    }
    float m = acc / fmaxf((float)cnt, 1.0f);
    meanb[(long)n * DIM + lane] = __float2bfloat16(m);
}

// ---------------------------------------------------------------------------
// GEMM + heads: per 64-node block compute
//   h = relu(mean@Wl0^T + x@Wr0^T + bl0)   (registers only)
//   s[n] = h.Wl1 ; t[n] = h.Wr1
// Register tile 4x4/thread; A^T and W^T staged in LDS (stride 68, float4).
// Two passes over K (pass0: mean/Wl0, pass1: x/Wr0) reusing the same LDS.
// ---------------------------------------------------------------------------
__global__ __launch_bounds__(256) void gemm_heads_kernel(
        const bf16* __restrict__ meanb, const void* __restrict__ x,
        const void* __restrict__ Wl0, const void* __restrict__ bl0,
        const void* __restrict__ Wr0, const void* __restrict__ Wl1,
        const void* __restrict__ Wr1,
        float* __restrict__ s, float* __restrict__ t,
        const int* __restrict__ flags) {
    __shared__ float AT[64][68];   // AT[k][m], stride 68 floats (16B-aligned rows)
    __shared__ float WT[64][68];   // WT[k][d]
    __shared__ float sRed[64], tRed[64], bl0s[64], wl1s[64], wr1s[64];
    const int isb = flags[0];
    const int tid = threadIdx.x;
    const int n0 = blockIdx.x * 64;

    if (tid < 64) {
        bl0s[tid] = loadF(bl0, tid, isb);
        wl1s[tid] = loadF(Wl1, tid, isb);
        wr1s[tid] = loadF(Wr1, tid, isb);
        sRed[tid] = 0.0f; tRed[tid] = 0.0f;
    }

    const int mi = (tid & 15) * 4;   // node offset within tile
    const int di = (tid >> 4) * 4;   // out-dim offset
    float c[4][4];

    #pragma unroll
    for (int pass = 0; pass < 2; ++pass) {
        for (int i = tid; i < 4096; i += 256) {
            int m = i >> 6, k = i & 63;
            int node = n0 + m;
            float av;
            if (pass == 0) av = (node < N_NODES) ? b2f(meanb[(long)node * DIM + k]) : 0.0f;
            else           av = (node < N_NODES) ? loadF(x, (long)node * DIM + k, isb) : 0.0f;
            AT[k][m] = av;
            // W[d][k] row-major, i = d*64+k with d=m
            WT[k][m] = loadF(pass == 0 ? Wl0 : Wr0, i, isb);
        }
        __syncthreads();
        if (pass == 0) {
            #pragma unroll
            for (int i = 0; i < 4; ++i)
                #pragma unroll
                for (int j = 0; j < 4; ++j)
                    c[i][j] = bl0s[di + j];
        }
        #pragma unroll 8
        for (int k = 0; k < 64; ++k) {
            float4 a = *(const float4*)&AT[k][mi];
            float4 w = *(const float4*)&WT[k][di];
            c[0][0] = fmaf(a.x, w.x, c[0][0]); c[0][1] = fmaf(a.x, w.y, c[0][1]);
            c[0][2] = fmaf(a.x, w.z, c[0][2]); c[0][3] = fmaf(a.x, w.w, c[0][3]);
            c[1][0] = fmaf(a.y, w.x, c[1][0]); c[1][1] = fmaf(a.y, w.y, c[1][1]);
            c[1][2] = fmaf(a.y, w.z, c[1][2]); c[1][3] = fmaf(a.y, w.w, c[1][3]);
            c[2][0] = fmaf(a.z, w.x, c[2][0]); c[2][1] = fmaf(a.z, w.y, c[2][1]);
            c[2][2] = fmaf(a.z, w.z, c[2][2]); c[2][3] = fmaf(a.z, w.w, c[2][3]);
            c[3][0] = fmaf(a.w, w.x, c[3][0]); c[3][1] = fmaf(a.w, w.y, c[3][1]);
            c[3][2] = fmaf(a.w, w.z, c[3][2]); c[3][3] = fmaf(a.w, w.w, c[3][3]);
        }
        __syncthreads();   // protect LDS before pass-1 overwrite / epilogue
    }

    // Epilogue: relu + dual dot-product head, LDS-atomic reduction per node.
    #pragma unroll
    for (int i = 0; i < 4; ++i) {
        float hs = 0.0f, ht = 0.0f;
        #pragma unroll
        for (int j = 0; j < 4; ++j) {
            float h = fmaxf(c[i][j], 0.0f);
            hs = fmaf(h, wl1s[di + j], hs);
            ht = fmaf(h, wr1s[di + j], ht);
        }
        atomicAdd(&sRed[mi + i], hs);
        atomicAdd(&tRed[mi + i], ht);
    }
    __syncthreads();
    if (tid < 64) {
        int node = n0 + tid;
        if (node < N_NODES) { s[node] = sRed[tid]; t[node] = tRed[tid]; }
    }
}

// ---------------------------------------------------------------------------
// Final: CSR-gather of s, mean, + bl1 + t, sigmoid, write both outputs.
// ---------------------------------------------------------------------------
__global__ void final_kernel(const float* __restrict__ s,
                             const float* __restrict__ t,
                             const int* __restrict__ rowstart,
                             const int* __restrict__ degi,
                             const int* __restrict__ csr,
                             const void* __restrict__ bl1,
                             void* __restrict__ out,
                             const int* __restrict__ flags) {
    const int isb = flags[0];
    int n = blockIdx.x * 256 + threadIdx.x;
    if (n >= N_NODES) return;
    int beg = rowstart[n], cnt = degi[n];
    float acc = 0.0f;
    for (int i = 0; i < cnt; ++i) acc += s[csr[beg + i]];
    float v = acc / fmaxf((float)cnt, 1.0f) + loadF(bl1, 0, isb) + t[n];
    float sg = 1.0f / (1.0f + expf(-v));
    if (isb) {
        ((bf16*)out)[n] = __float2bfloat16(v);
        ((bf16*)out)[N_NODES + n] = __float2bfloat16(sg);
    } else {
        ((float*)out)[n] = v;
        ((float*)out)[N_NODES + n] = sg;
    }
}

extern "C" void kernel_launch(void* const* d_in, const int* in_sizes, int n_in,
                              void* d_out, int out_size, void* d_ws, size_t ws_size,
                              hipStream_t stream) {
    const void* x   = d_in[0];
    const int*  ei  = (const int*)d_in[1];
    const void* Wl0 = d_in[2];
    const void* bl0 = d_in[3];
    const void* Wr0 = d_in[4];
    const void* Wl1 = d_in[5];
    const void* bl1 = d_in[6];
    const void* Wr1 = d_in[7];

    // Workspace layout (18.9 MB):
    //   flags    @0         (256 B)       } zeroed
    //   degi     @256       (400,000 B)   } zeroed
    //   cursor   @400,256   (400,000 B)   } zeroed   -> one 800,256 B memset
    //   rowstart @800,256   (400,000 B)
    //   bsum     @1,200,256 (4,096 B)
    //   s        @1,204,352 (400,000 B)
    //   t        @1,604,352 (400,000 B)
    //   csr      @2,004,352 (4,000,000 B)
    //   meanb    @6,004,352 (12,800,000 B)
    char* ws = (char*)d_ws;
    int*   flags    = (int*)(ws);
    int*   degi     = (int*)(ws + 256);
    int*   cursor   = (int*)(ws + 400256);
    int*   rowstart = (int*)(ws + 800256);
    int*   bsum     = (int*)(ws + 1200256);
    float* s        = (float*)(ws + 1204352);
    float* t        = (float*)(ws + 1604352);
    int*   csr      = (int*)(ws + 2004352);
    bf16*  meanb    = (bf16*)(ws + 6004352);

    hipMemsetAsync(ws, 0, 800256, stream);

    const int EB = (N_EDGES + 255) / 256;      // 3907
    detect_kernel<<<1, 256, 0, stream>>>(x, ei, flags);
    hist_kernel<<<EB, 256, 0, stream>>>(ei, degi, flags);
    scan1_kernel<<<SCAN_BLOCKS, 256, 0, stream>>>(degi, rowstart, bsum);
    scan2_kernel<<<1, 512, 0, stream>>>(bsum);
    scan3_kernel<<<SCAN_BLOCKS, 256, 0, stream>>>(rowstart, bsum);
    fill_kernel<<<EB, 256, 0, stream>>>(ei, rowstart, cursor, csr, flags);
    aggregate_kernel<<<(N_NODES + 3) / 4, 256, 0, stream>>>(x, rowstart, degi, csr,
                                                            meanb, flags);
    gemm_heads_kernel<<<(N_NODES + 63) / 64, 256, 0, stream>>>(meanb, x, Wl0, bl0,
                                                               Wr0, Wl1, Wr1, s, t, flags);
    final_kernel<<<SCAN_BLOCKS, 256, 0, stream>>>(s, t, rowstart, degi, csr, bl1,
                                                  d_out, flags);
}

// Round 7
// 292.359 us; speedup vs baseline: 2.1001x; 1.3091x over previous
//
#include <hip/hip_runtime.h>
#include <hip/hip_bf16.h>
#include <math.h>

#define N_NODES 100000
#define N_EDGES 1000000
#define DIM 64
#define SCAN_BLOCKS 391   // ceil(N_NODES/256)

// Device dtypes (established empirically R1-R6):
//   float arrays : fp32   (R1 bf16-read NaN'd; R2/R3 runtime-detect passed)
//   edge_index   : int32  (R5/R6 int64-stride reads faulted OOB -> SIGABRT)
//   output       : fp32
typedef __hip_bfloat16 bf16;

__device__ __forceinline__ float b2f(bf16 v) { return __bfloat162float(v); }

__device__ __forceinline__ unsigned int packbf2(float a, float b) {
    bf16 x = __float2bfloat16(a), y = __float2bfloat16(b);
    unsigned short ux = *(unsigned short*)&x, uy = *(unsigned short*)&y;
    return (unsigned int)ux | ((unsigned int)uy << 16);
}

__device__ __forceinline__ float2 upk(unsigned int u) {
    unsigned short lo = (unsigned short)(u & 0xffff);
    unsigned short hi = (unsigned short)(u >> 16);
    bf16 a = *(bf16*)&lo, b = *(bf16*)&hi;
    return make_float2(b2f(a), b2f(b));
}

__device__ __forceinline__ int clampN(int v) {
    return v < 0 ? 0 : (v >= N_NODES ? N_NODES - 1 : v);
}

// ---------------------------------------------------------------------------
// CSR build: histogram -> scan (2 kernels; block offsets folded into readers)
// ---------------------------------------------------------------------------
__global__ void hist_kernel(const int* __restrict__ ei, int* __restrict__ degi) {
    int e = blockIdx.x * blockDim.x + threadIdx.x;
    if (e < N_EDGES) {
        int dst = clampN(ei[N_EDGES + e]);
        atomicAdd(&degi[dst], 1);
    }
}

__global__ void scan1_kernel(const int* __restrict__ degi,
                             int* __restrict__ rowstart, int* __restrict__ bsum) {
    __shared__ int sc[256];
    int t = threadIdx.x;
    int i = blockIdx.x * 256 + t;
    int v = (i < N_NODES) ? degi[i] : 0;
    sc[t] = v;
    __syncthreads();
    #pragma unroll
    for (int off = 1; off < 256; off <<= 1) {
        int u = (t >= off) ? sc[t - off] : 0;
        __syncthreads();
        sc[t] += u;
        __syncthreads();
    }
    if (i < N_NODES) rowstart[i] = sc[t] - v;   // exclusive within block
    if (t == 255) bsum[blockIdx.x] = sc[t];
}

__global__ void scan2_kernel(int* __restrict__ bsum) {
    __shared__ int sc[512];
    int t = threadIdx.x;
    int v = (t < SCAN_BLOCKS) ? bsum[t] : 0;
    sc[t] = v;
    __syncthreads();
    #pragma unroll
    for (int off = 1; off < 512; off <<= 1) {
        int u = (t >= off) ? sc[t - off] : 0;
        __syncthreads();
        sc[t] += u;
        __syncthreads();
    }
    if (t < SCAN_BLOCKS) bsum[t] = sc[t] - v;   // exclusive
}

__global__ void fill_kernel(const int* __restrict__ ei,
                            const int* __restrict__ rowstart,
                            const int* __restrict__ bsum,
                            int* __restrict__ cursor, int* __restrict__ csr) {
    int e = blockIdx.x * blockDim.x + threadIdx.x;
    if (e < N_EDGES) {
        int src = clampN(ei[e]);
        int dst = clampN(ei[N_EDGES + e]);
        int pos = atomicAdd(&cursor[dst], 1);
        csr[rowstart[dst] + bsum[dst >> 8] + pos] = src;
    }
}

// ---------------------------------------------------------------------------
// Aggregate: one wave per node, two 32-lane halves each owning one edge row
// per issue (lane loads float2 = 2 fp32 dims). 2 independent accumulators =>
// up to 4 row-gathers in flight. Writes bf16 mean row (128 B by half-wave).
// ---------------------------------------------------------------------------
__global__ void aggregate_kernel(const float2* __restrict__ x2,
                                 const int* __restrict__ rowstart,
                                 const int* __restrict__ bsum,
                                 const int* __restrict__ degi,
                                 const int* __restrict__ csr,
                                 unsigned int* __restrict__ mu) {
    int tid = threadIdx.x;
    int half = (tid >> 5) & 1;
    int l32 = tid & 31;
    int n = blockIdx.x * (blockDim.x >> 6) + (tid >> 6);
    if (n >= N_NODES) return;
    int beg = rowstart[n] + bsum[n >> 8];
    int cnt = degi[n];

    float2 a0 = make_float2(0.f, 0.f), a1 = make_float2(0.f, 0.f);
    int i = 0;
    for (; i + 4 <= cnt; i += 4) {
        int s0 = csr[beg + i + half];
        int s1 = csr[beg + i + 2 + half];
        float2 f0 = x2[(long)s0 * 32 + l32];
        float2 f1 = x2[(long)s1 * 32 + l32];
        a0.x += f0.x; a0.y += f0.y;
        a1.x += f1.x; a1.y += f1.y;
    }
    if (i + 2 <= cnt) {
        int s0 = csr[beg + i + half];
        float2 f0 = x2[(long)s0 * 32 + l32];
        a0.x += f0.x; a0.y += f0.y;
        i += 2;
    }
    if (i < cnt && half == 0) {
        int s0 = csr[beg + i];
        float2 f0 = x2[(long)s0 * 32 + l32];
        a0.x += f0.x; a0.y += f0.y;
    }
    float sx = a0.x + a1.x, sy = a0.y + a1.y;
    sx += __shfl_xor(sx, 32, 64);
    sy += __shfl_xor(sy, 32, 64);
    if (half == 0) {
        float inv = 1.0f / fmaxf((float)cnt, 1.0f);
        mu[(long)n * 32 + l32] = packbf2(sx * inv, sy * inv);
    }
}

// ---------------------------------------------------------------------------
// GEMM + heads: per 64-node block compute
//   h = relu(mean@Wl0^T + x@Wr0^T + bl0)   (registers only)
//   s[n] = h.Wl1 ; t[n] = h.Wr1
// Register tile 4x4/thread; A^T and W^T staged in LDS (stride 68, float4).
// pass0: A = bf16 mean, W = Wl0 (fp32); pass1: A = fp32 x, W = Wr0.
// ---------------------------------------------------------------------------
__global__ __launch_bounds__(256) void gemm_heads_kernel(
        const unsigned int* __restrict__ mu, const float* __restrict__ xf,
        const float* __restrict__ Wl0, const float* __restrict__ bl0,
        const float* __restrict__ Wr0, const float* __restrict__ Wl1,
        const float* __restrict__ Wr1,
        float* __restrict__ s, float* __restrict__ t) {
    __shared__ float AT[64][68];
    __shared__ float WT[64][68];
    __shared__ float sRed[64], tRed[64], bl0s[64], wl1s[64], wr1s[64];
    const int tid = threadIdx.x;
    const int n0 = blockIdx.x * 64;

    if (tid < 64) {
        bl0s[tid] = bl0[tid];
        wl1s[tid] = Wl1[tid];
        wr1s[tid] = Wr1[tid];
        sRed[tid] = 0.0f; tRed[tid] = 0.0f;
    }

    const int mi = (tid & 15) * 4;
    const int di = (tid >> 4) * 4;
    float c[4][4];

    #pragma unroll
    for (int pass = 0; pass < 2; ++pass) {
        const float* W = (pass == 0) ? Wl0 : Wr0;
        // A-tile: mean (bf16 pairs) on pass 0, x (fp32) on pass 1
        if (pass == 0) {
            for (int i = tid; i < 2048; i += 256) {   // 64 nodes x 32 pairs
                int m = i >> 5, p = i & 31;
                int node = n0 + m;
                float2 f = (node < N_NODES) ? upk(mu[(long)node * 32 + p])
                                            : make_float2(0.f, 0.f);
                AT[2 * p][m] = f.x;
                AT[2 * p + 1][m] = f.y;
            }
        } else {
            for (int i = tid; i < 4096; i += 256) {
                int m = i >> 6, k = i & 63;
                int node = n0 + m;
                AT[k][m] = (node < N_NODES) ? xf[(long)node * DIM + k] : 0.0f;
            }
        }
        for (int i = tid; i < 4096; i += 256) {
            int m = i >> 6, k = i & 63;
            WT[k][m] = W[i];   // W[d][k] row-major, d=m
        }
        __syncthreads();
        if (pass == 0) {
            #pragma unroll
            for (int i = 0; i < 4; ++i)
                #pragma unroll
                for (int j = 0; j < 4; ++j)
                    c[i][j] = bl0s[di + j];
        }
        #pragma unroll 8
        for (int k = 0; k < 64; ++k) {
            float4 a = *(const float4*)&AT[k][mi];
            float4 w = *(const float4*)&WT[k][di];
            c[0][0] = fmaf(a.x, w.x, c[0][0]); c[0][1] = fmaf(a.x, w.y, c[0][1]);
            c[0][2] = fmaf(a.x, w.z, c[0][2]); c[0][3] = fmaf(a.x, w.w, c[0][3]);
            c[1][0] = fmaf(a.y, w.x, c[1][0]); c[1][1] = fmaf(a.y, w.y, c[1][1]);
            c[1][2] = fmaf(a.y, w.z, c[1][2]); c[1][3] = fmaf(a.y, w.w, c[1][3]);
            c[2][0] = fmaf(a.z, w.x, c[2][0]); c[2][1] = fmaf(a.z, w.y, c[2][1]);
            c[2][2] = fmaf(a.z, w.z, c[2][2]); c[2][3] = fmaf(a.z, w.w, c[2][3]);
            c[3][0] = fmaf(a.w, w.x, c[3][0]); c[3][1] = fmaf(a.w, w.y, c[3][1]);
            c[3][2] = fmaf(a.w, w.z, c[3][2]); c[3][3] = fmaf(a.w, w.w, c[3][3]);
        }
        __syncthreads();
    }

    #pragma unroll
    for (int i = 0; i < 4; ++i) {
        float hs = 0.0f, ht = 0.0f;
        #pragma unroll
        for (int j = 0; j < 4; ++j) {
            float h = fmaxf(c[i][j], 0.0f);
            hs = fmaf(h, wl1s[di + j], hs);
            ht = fmaf(h, wr1s[di + j], ht);
        }
        atomicAdd(&sRed[mi + i], hs);
        atomicAdd(&tRed[mi + i], ht);
    }
    __syncthreads();
    if (tid < 64) {
        int node = n0 + tid;
        if (node < N_NODES) { s[node] = sRed[tid]; t[node] = tRed[tid]; }
    }
}

// ---------------------------------------------------------------------------
// Final: CSR-gather of s (4-wide ILP), mean, + bl1 + t, sigmoid, fp32 out.
// ---------------------------------------------------------------------------
__global__ void final_kernel(const float* __restrict__ s,
                             const float* __restrict__ t,
                             const int* __restrict__ rowstart,
                             const int* __restrict__ bsum,
                             const int* __restrict__ degi,
                             const int* __restrict__ csr,
                             const float* __restrict__ bl1,
                             float* __restrict__ out) {
    int n = blockIdx.x * 256 + threadIdx.x;
    if (n >= N_NODES) return;
    int beg = rowstart[n] + bsum[n >> 8];
    int cnt = degi[n];
    float acc = 0.0f;
    int i = 0;
    for (; i + 4 <= cnt; i += 4) {
        int e0 = csr[beg + i], e1 = csr[beg + i + 1];
        int e2 = csr[beg + i + 2], e3 = csr[beg + i + 3];
        acc += s[e0] + s[e1] + s[e2] + s[e3];
    }
    for (; i < cnt; ++i) acc += s[csr[beg + i]];
    float v = acc / fmaxf((float)cnt, 1.0f) + bl1[0] + t[n];
    float sg = 1.0f / (1.0f + expf(-v));
    out[n] = v;
    out[N_NODES + n] = sg;
}

extern "C" void kernel_launch(void* const* d_in, const int* in_sizes, int n_in,
                              void* d_out, int out_size, void* d_ws, size_t ws_size,
                              hipStream_t stream) {
    const float* x   = (const float*)d_in[0];
    const int*   ei  = (const int*)d_in[1];   // int32, [2,E] flat: src row, dst row
    const float* Wl0 = (const float*)d_in[2];
    const float* bl0 = (const float*)d_in[3];
    const float* Wr0 = (const float*)d_in[4];
    const float* Wl1 = (const float*)d_in[5];
    const float* bl1 = (const float*)d_in[6];
    const float* Wr1 = (const float*)d_in[7];
    float* out = (float*)d_out;

    // Workspace layout (18.8 MB; every buffer read is written earlier in the
    // same launch):
    //   degi     @0          (400,000)  } zeroed together
    //   cursor   @400,000    (400,000)  }
    //   rowstart @800,000    (400,000)
    //   bsum     @1,200,000  (4,096)
    //   s        @1,204,096  (400,000)
    //   t        @1,604,096  (400,000)
    //   csr      @2,004,096  (4,000,000)
    //   meanb    @6,004,096  (12,800,000)  bf16 mean rows
    char* ws = (char*)d_ws;
    int*   degi     = (int*)(ws);
    int*   cursor   = (int*)(ws + 400000);
    int*   rowstart = (int*)(ws + 800000);
    int*   bsum     = (int*)(ws + 1200000);
    float* s        = (float*)(ws + 1204096);
    float* t        = (float*)(ws + 1604096);
    int*   csr      = (int*)(ws + 2004096);
    unsigned int* mu = (unsigned int*)(ws + 6004096);

    (void)hipMemsetAsync(ws, 0, 800000, stream);

    const int EB = (N_EDGES + 255) / 256;      // 3907
    hist_kernel<<<EB, 256, 0, stream>>>(ei, degi);
    scan1_kernel<<<SCAN_BLOCKS, 256, 0, stream>>>(degi, rowstart, bsum);
    scan2_kernel<<<1, 512, 0, stream>>>(bsum);
    fill_kernel<<<EB, 256, 0, stream>>>(ei, rowstart, bsum, cursor, csr);
    aggregate_kernel<<<25000, 256, 0, stream>>>((const float2*)x, rowstart,
                                                bsum, degi, csr, mu);
    gemm_heads_kernel<<<(N_NODES + 63) / 64, 256, 0, stream>>>(mu, x, Wl0, bl0,
                                                               Wr0, Wl1, Wr1, s, t);
    final_kernel<<<SCAN_BLOCKS, 256, 0, stream>>>(s, t, rowstart, bsum, degi, csr,
                                                  bl1, out);
}

// Round 8
// 278.581 us; speedup vs baseline: 2.2040x; 1.0495x over previous
//
#include <hip/hip_runtime.h>
#include <hip/hip_bf16.h>
#include <math.h>

#define N_NODES 100000
#define N_EDGES 1000000
#define DIM 64
#define SCAN_BLOCKS 391   // ceil(N_NODES/256)
#define N_TILES 1563      // ceil(N_NODES/64)

// Device dtypes (established empirically R1-R7): fp32 floats, int32 indices,
// fp32 output.
typedef __hip_bfloat16 bf16;

__device__ __forceinline__ float b2f(bf16 v) { return __bfloat162float(v); }

__device__ __forceinline__ unsigned int packbf2(float a, float b) {
    bf16 x = __float2bfloat16(a), y = __float2bfloat16(b);
    unsigned short ux = *(unsigned short*)&x, uy = *(unsigned short*)&y;
    return (unsigned int)ux | ((unsigned int)uy << 16);
}

__device__ __forceinline__ float2 upk(unsigned int u) {
    unsigned short lo = (unsigned short)(u & 0xffff);
    unsigned short hi = (unsigned short)(u >> 16);
    bf16 a = *(bf16*)&lo, b = *(bf16*)&hi;
    return make_float2(b2f(a), b2f(b));
}

__device__ __forceinline__ int clampN(int v) {
    return v < 0 ? 0 : (v >= N_NODES ? N_NODES - 1 : v);
}

// ---------------------------------------------------------------------------
// CSR build. hist/fill: 4 edges per thread (int4 loads) for 4 independent
// atomic chains in flight (fill was latency-bound at 1 edge/thread: R7
// VALUBusy 0.5%).
// ---------------------------------------------------------------------------
__global__ void hist_kernel(const int* __restrict__ ei, int* __restrict__ degi) {
    int idx = blockIdx.x * blockDim.x + threadIdx.x;
    if (idx < N_EDGES / 4) {
        int4 d4 = ((const int4*)(ei + N_EDGES))[idx];
        atomicAdd(&degi[clampN(d4.x)], 1);
        atomicAdd(&degi[clampN(d4.y)], 1);
        atomicAdd(&degi[clampN(d4.z)], 1);
        atomicAdd(&degi[clampN(d4.w)], 1);
    }
}

__global__ void scan1_kernel(const int* __restrict__ degi,
                             int* __restrict__ rowstart, int* __restrict__ bsum) {
    __shared__ int sc[256];
    int t = threadIdx.x;
    int i = blockIdx.x * 256 + t;
    int v = (i < N_NODES) ? degi[i] : 0;
    sc[t] = v;
    __syncthreads();
    #pragma unroll
    for (int off = 1; off < 256; off <<= 1) {
        int u = (t >= off) ? sc[t - off] : 0;
        __syncthreads();
        sc[t] += u;
        __syncthreads();
    }
    if (i < N_NODES) rowstart[i] = sc[t] - v;   // exclusive within block
    if (t == 255) bsum[blockIdx.x] = sc[t];
}

__global__ void scan2_kernel(int* __restrict__ bsum) {
    __shared__ int sc[512];
    int t = threadIdx.x;
    int v = (t < SCAN_BLOCKS) ? bsum[t] : 0;
    sc[t] = v;
    __syncthreads();
    #pragma unroll
    for (int off = 1; off < 512; off <<= 1) {
        int u = (t >= off) ? sc[t - off] : 0;
        __syncthreads();
        sc[t] += u;
        __syncthreads();
    }
    if (t < SCAN_BLOCKS) bsum[t] = sc[t] - v;   // exclusive
}

__global__ void fill_kernel(const int* __restrict__ ei,
                            const int* __restrict__ rowstart,
                            const int* __restrict__ bsum,
                            int* __restrict__ cursor, int* __restrict__ csr) {
    int idx = blockIdx.x * blockDim.x + threadIdx.x;
    if (idx < N_EDGES / 4) {
        int4 s4 = ((const int4*)ei)[idx];
        int4 d4 = ((const int4*)(ei + N_EDGES))[idx];
        int d, p;
        d = clampN(d4.x); p = atomicAdd(&cursor[d], 1);
        csr[rowstart[d] + bsum[d >> 8] + p] = clampN(s4.x);
        d = clampN(d4.y); p = atomicAdd(&cursor[d], 1);
        csr[rowstart[d] + bsum[d >> 8] + p] = clampN(s4.y);
        d = clampN(d4.z); p = atomicAdd(&cursor[d], 1);
        csr[rowstart[d] + bsum[d >> 8] + p] = clampN(s4.z);
        d = clampN(d4.w); p = atomicAdd(&cursor[d], 1);
        csr[rowstart[d] + bsum[d >> 8] + p] = clampN(s4.w);
    }
}

// ---------------------------------------------------------------------------
// Aggregate: one wave per node; 4 quarter-waves (16 lanes, float4 = 4 dims)
// each own one edge row per issue, 2 accumulators => up to 8 row-gathers in
// flight. Writes bf16 mean row (uint2 per lane).
// ---------------------------------------------------------------------------
__global__ void aggregate_kernel(const float4* __restrict__ x4,
                                 const int* __restrict__ rowstart,
                                 const int* __restrict__ bsum,
                                 const int* __restrict__ degi,
                                 const int* __restrict__ csr,
                                 uint2* __restrict__ mu2) {
    int tid = threadIdx.x;
    int q = (tid >> 4) & 3;
    int l16 = tid & 15;
    int n = blockIdx.x * (blockDim.x >> 6) + (tid >> 6);
    if (n >= N_NODES) return;
    int beg = rowstart[n] + bsum[n >> 8];
    int cnt = degi[n];

    float4 a0 = make_float4(0.f, 0.f, 0.f, 0.f);
    float4 a1 = make_float4(0.f, 0.f, 0.f, 0.f);
    int i = 0;
    for (; i + 8 <= cnt; i += 8) {
        int s0 = csr[beg + i + q];
        int s1 = csr[beg + i + 4 + q];
        float4 f0 = x4[(long)s0 * 16 + l16];
        float4 f1 = x4[(long)s1 * 16 + l16];
        a0.x += f0.x; a0.y += f0.y; a0.z += f0.z; a0.w += f0.w;
        a1.x += f1.x; a1.y += f1.y; a1.z += f1.z; a1.w += f1.w;
    }
    if (i + q < cnt) {
        float4 f0 = x4[(long)csr[beg + i + q] * 16 + l16];
        a0.x += f0.x; a0.y += f0.y; a0.z += f0.z; a0.w += f0.w;
    }
    if (i + 4 + q < cnt) {
        float4 f1 = x4[(long)csr[beg + i + 4 + q] * 16 + l16];
        a1.x += f1.x; a1.y += f1.y; a1.z += f1.z; a1.w += f1.w;
    }
    float4 a = make_float4(a0.x + a1.x, a0.y + a1.y, a0.z + a1.z, a0.w + a1.w);
    #pragma unroll
    for (int off = 16; off <= 32; off <<= 1) {
        a.x += __shfl_xor(a.x, off, 64);
        a.y += __shfl_xor(a.y, off, 64);
        a.z += __shfl_xor(a.z, off, 64);
        a.w += __shfl_xor(a.w, off, 64);
    }
    if (q == 0) {
        float inv = 1.0f / fmaxf((float)cnt, 1.0f);
        mu2[(long)n * 16 + l16] =
            make_uint2(packbf2(a.x * inv, a.y * inv), packbf2(a.z * inv, a.w * inv));
    }
}

// ---------------------------------------------------------------------------
// GEMM + heads, weight-resident version. Per block: stage WT[128][68] =
// [Wl0 | Wr0]^T once, then grid-stride over 64-node tiles:
//   h = relu(mean@Wl0^T + x@Wr0^T + bl0)  (registers; K split in two halves
//   reusing AT[64][68])
//   s[n] = h.Wl1 ; t[n] = h.Wr1
// 4x4 register tile/thread; LDS ~53.5 KB -> 3 blocks/CU.
// ---------------------------------------------------------------------------
__global__ __launch_bounds__(256) void gemm_heads_kernel(
        const unsigned int* __restrict__ mu, const float* __restrict__ xf,
        const float* __restrict__ Wl0, const float* __restrict__ bl0,
        const float* __restrict__ Wr0, const float* __restrict__ Wl1,
        const float* __restrict__ Wr1,
        float* __restrict__ s, float* __restrict__ t) {
    __shared__ float WT[128][68];   // WT[k][d]: k<64 -> Wl0[d][k], k>=64 -> Wr0[d][k-64]
    __shared__ float AT[64][68];    // AT[k][m]
    __shared__ float sRed[64], tRed[64], bl0s[64], wl1s[64], wr1s[64];
    const int tid = threadIdx.x;

    for (int i = tid; i < 4096; i += 256) {
        int d = i >> 6, k = i & 63;
        WT[k][d] = Wl0[i];
        WT[64 + k][d] = Wr0[i];
    }
    if (tid < 64) {
        bl0s[tid] = bl0[tid];
        wl1s[tid] = Wl1[tid];
        wr1s[tid] = Wr1[tid];
    }
    // barrier folded into first tile's B1

    const int mi = (tid & 15) * 4;
    const int di = (tid >> 4) * 4;

    for (int tile = blockIdx.x; tile < N_TILES; tile += gridDim.x) {
        const int n0 = tile * 64;
        if (tid < 64) { sRed[tid] = 0.0f; tRed[tid] = 0.0f; }
        // stage A: mean (bf16 pairs), K-half 0
        for (int i = tid; i < 2048; i += 256) {
            int m = i >> 5, p = i & 31;
            int node = n0 + m;
            float2 f = (node < N_NODES) ? upk(mu[(long)node * 32 + p])
                                        : make_float2(0.f, 0.f);
            AT[2 * p][m] = f.x;
            AT[2 * p + 1][m] = f.y;
        }
        __syncthreads();   // B1: W + A-mean + sRed-zero visible

        float c[4][4];
        #pragma unroll
        for (int i = 0; i < 4; ++i)
            #pragma unroll
            for (int j = 0; j < 4; ++j)
                c[i][j] = bl0s[di + j];

        #pragma unroll 8
        for (int k = 0; k < 64; ++k) {
            float4 a = *(const float4*)&AT[k][mi];
            float4 w = *(const float4*)&WT[k][di];
            c[0][0] = fmaf(a.x, w.x, c[0][0]); c[0][1] = fmaf(a.x, w.y, c[0][1]);
            c[0][2] = fmaf(a.x, w.z, c[0][2]); c[0][3] = fmaf(a.x, w.w, c[0][3]);
            c[1][0] = fmaf(a.y, w.x, c[1][0]); c[1][1] = fmaf(a.y, w.y, c[1][1]);
            c[1][2] = fmaf(a.y, w.z, c[1][2]); c[1][3] = fmaf(a.y, w.w, c[1][3]);
            c[2][0] = fmaf(a.z, w.x, c[2][0]); c[2][1] = fmaf(a.z, w.y, c[2][1]);
            c[2][2] = fmaf(a.z, w.z, c[2][2]); c[2][3] = fmaf(a.z, w.w, c[2][3]);
            c[3][0] = fmaf(a.w, w.x, c[3][0]); c[3][1] = fmaf(a.w, w.y, c[3][1]);
            c[3][2] = fmaf(a.w, w.z, c[3][2]); c[3][3] = fmaf(a.w, w.w, c[3][3]);
        }
        __syncthreads();   // B2: AT reads done before restage

        // stage A: x (fp32), K-half 1
        for (int i = tid; i < 4096; i += 256) {
            int m = i >> 6, k = i & 63;
            int node = n0 + m;
            AT[k][m] = (node < N_NODES) ? xf[(long)node * DIM + k] : 0.0f;
        }
        __syncthreads();   // B3

        #pragma unroll 8
        for (int k = 0; k < 64; ++k) {
            float4 a = *(const float4*)&AT[k][mi];
            float4 w = *(const float4*)&WT[64 + k][di];
            c[0][0] = fmaf(a.x, w.x, c[0][0]); c[0][1] = fmaf(a.x, w.y, c[0][1]);
            c[0][2] = fmaf(a.x, w.z, c[0][2]); c[0][3] = fmaf(a.x, w.w, c[0][3]);
            c[1][0] = fmaf(a.y, w.x, c[1][0]); c[1][1] = fmaf(a.y, w.y, c[1][1]);
            c[1][2] = fmaf(a.y, w.z, c[1][2]); c[1][3] = fmaf(a.y, w.w, c[1][3]);
            c[2][0] = fmaf(a.z, w.x, c[2][0]); c[2][1] = fmaf(a.z, w.y, c[2][1]);
            c[2][2] = fmaf(a.z, w.z, c[2][2]); c[2][3] = fmaf(a.z, w.w, c[2][3]);
            c[3][0] = fmaf(a.w, w.x, c[3][0]); c[3][1] = fmaf(a.w, w.y, c[3][1]);
            c[3][2] = fmaf(a.w, w.z, c[3][2]); c[3][3] = fmaf(a.w, w.w, c[3][3]);
        }

        // epilogue: relu + dual head dots, LDS reduction per node
        #pragma unroll
        for (int i = 0; i < 4; ++i) {
            float hs = 0.0f, ht = 0.0f;
            #pragma unroll
            for (int j = 0; j < 4; ++j) {
                float h = fmaxf(c[i][j], 0.0f);
                hs = fmaf(h, wl1s[di + j], hs);
                ht = fmaf(h, wr1s[di + j], ht);
            }
            atomicAdd(&sRed[mi + i], hs);
            atomicAdd(&tRed[mi + i], ht);
        }
        __syncthreads();   // B4: reductions complete
        if (tid < 64) {
            int node = n0 + tid;
            if (node < N_NODES) { s[node] = sRed[tid]; t[node] = tRed[tid]; }
        }
        __syncthreads();   // B5: sRed/AT safe to reuse next tile
    }
}

// ---------------------------------------------------------------------------
// Final: CSR-gather of s (4-wide ILP), mean, + bl1 + t, sigmoid, fp32 out.
// ---------------------------------------------------------------------------
__global__ void final_kernel(const float* __restrict__ s,
                             const float* __restrict__ t,
                             const int* __restrict__ rowstart,
                             const int* __restrict__ bsum,
                             const int* __restrict__ degi,
                             const int* __restrict__ csr,
                             const float* __restrict__ bl1,
                             float* __restrict__ out) {
    int n = blockIdx.x * 256 + threadIdx.x;
    if (n >= N_NODES) return;
    int beg = rowstart[n] + bsum[n >> 8];
    int cnt = degi[n];
    float acc = 0.0f;
    int i = 0;
    for (; i + 4 <= cnt; i += 4) {
        int e0 = csr[beg + i], e1 = csr[beg + i + 1];
        int e2 = csr[beg + i + 2], e3 = csr[beg + i + 3];
        acc += s[e0] + s[e1] + s[e2] + s[e3];
    }
    for (; i < cnt; ++i) acc += s[csr[beg + i]];
    float v = acc / fmaxf((float)cnt, 1.0f) + bl1[0] + t[n];
    float sg = 1.0f / (1.0f + expf(-v));
    out[n] = v;
    out[N_NODES + n] = sg;
}

extern "C" void kernel_launch(void* const* d_in, const int* in_sizes, int n_in,
                              void* d_out, int out_size, void* d_ws, size_t ws_size,
                              hipStream_t stream) {
    const float* x   = (const float*)d_in[0];
    const int*   ei  = (const int*)d_in[1];   // int32, [2,E] flat: src row, dst row
    const float* Wl0 = (const float*)d_in[2];
    const float* bl0 = (const float*)d_in[3];
    const float* Wr0 = (const float*)d_in[4];
    const float* Wl1 = (const float*)d_in[5];
    const float* bl1 = (const float*)d_in[6];
    const float* Wr1 = (const float*)d_in[7];
    float* out = (float*)d_out;

    // Workspace layout (18.8 MB):
    //   degi     @0          (400,000)  } zeroed together
    //   cursor   @400,000    (400,000)  }
    //   rowstart @800,000    (400,000)
    //   bsum     @1,200,000  (4,096)
    //   s        @1,204,096  (400,000)
    //   t        @1,604,096  (400,000)
    //   csr      @2,004,096  (4,000,000)
    //   mu       @6,004,096  (12,800,000)  bf16 mean rows
    char* ws = (char*)d_ws;
    int*   degi     = (int*)(ws);
    int*   cursor   = (int*)(ws + 400000);
    int*   rowstart = (int*)(ws + 800000);
    int*   bsum     = (int*)(ws + 1200000);
    float* s        = (float*)(ws + 1204096);
    float* t        = (float*)(ws + 1604096);
    int*   csr      = (int*)(ws + 2004096);
    unsigned int* mu = (unsigned int*)(ws + 6004096);

    (void)hipMemsetAsync(ws, 0, 800000, stream);

    const int EB4 = (N_EDGES / 4 + 255) / 256;  // 977
    hist_kernel<<<EB4, 256, 0, stream>>>(ei, degi);
    scan1_kernel<<<SCAN_BLOCKS, 256, 0, stream>>>(degi, rowstart, bsum);
    scan2_kernel<<<1, 512, 0, stream>>>(bsum);
    fill_kernel<<<EB4, 256, 0, stream>>>(ei, rowstart, bsum, cursor, csr);
    aggregate_kernel<<<25000, 256, 0, stream>>>((const float4*)x, rowstart,
                                                bsum, degi, csr, (uint2*)mu);
    gemm_heads_kernel<<<768, 256, 0, stream>>>(mu, x, Wl0, bl0, Wr0, Wl1, Wr1,
                                               s, t);
    final_kernel<<<SCAN_BLOCKS, 256, 0, stream>>>(s, t, rowstart, bsum, degi, csr,
                                                  bl1, out);
}

// Round 9
// 219.626 us; speedup vs baseline: 2.7956x; 1.2684x over previous
//
#include <hip/hip_runtime.h>
#include <hip/hip_bf16.h>
#include <math.h>

#define N_NODES 100000
#define N_EDGES 1000000
#define DIM 64
#define SCAN_BLOCKS 391   // ceil(N_NODES/256)

// Device dtypes (established empirically R1-R8): fp32 floats, int32 indices,
// fp32 output.
typedef __hip_bfloat16 bf16;
typedef __attribute__((ext_vector_type(8))) short short8;
typedef __attribute__((ext_vector_type(4))) float floatx4;

__device__ __forceinline__ float b2f(bf16 v) { return __bfloat162float(v); }

__device__ __forceinline__ unsigned int packbf2(float a, float b) {
    bf16 x = __float2bfloat16(a), y = __float2bfloat16(b);
    unsigned short ux = *(unsigned short*)&x, uy = *(unsigned short*)&y;
    return (unsigned int)ux | ((unsigned int)uy << 16);
}

__device__ __forceinline__ short f2bs(float v) {
    bf16 x = __float2bfloat16(v);
    return *(short*)&x;
}

__device__ __forceinline__ float2 upk(unsigned int u) {
    unsigned short lo = (unsigned short)(u & 0xffff);
    unsigned short hi = (unsigned short)(u >> 16);
    bf16 a = *(bf16*)&lo, b = *(bf16*)&hi;
    return make_float2(b2f(a), b2f(b));
}

__device__ __forceinline__ int clampN(int v) {
    return v < 0 ? 0 : (v >= N_NODES ? N_NODES - 1 : v);
}

// ---------------------------------------------------------------------------
// hist: degree histogram + per-edge rank capture (pos = atomic return value).
// This removes the atomic from fill entirely (R8: fill latency-bound on its
// atomic->store dependent chain).
// ---------------------------------------------------------------------------
__global__ void hist_kernel(const int* __restrict__ ei, int* __restrict__ degi,
                            int* __restrict__ pos) {
    int idx = blockIdx.x * blockDim.x + threadIdx.x;
    if (idx < N_EDGES / 4) {
        int4 d4 = ((const int4*)(ei + N_EDGES))[idx];
        int4 p;
        p.x = atomicAdd(&degi[clampN(d4.x)], 1);
        p.y = atomicAdd(&degi[clampN(d4.y)], 1);
        p.z = atomicAdd(&degi[clampN(d4.z)], 1);
        p.w = atomicAdd(&degi[clampN(d4.w)], 1);
        ((int4*)pos)[idx] = p;
    }
}

__global__ void scan1_kernel(const int* __restrict__ degi,
                             int* __restrict__ rowstart, int* __restrict__ bsum) {
    __shared__ int sc[256];
    int t = threadIdx.x;
    int i = blockIdx.x * 256 + t;
    int v = (i < N_NODES) ? degi[i] : 0;
    sc[t] = v;
    __syncthreads();
    #pragma unroll
    for (int off = 1; off < 256; off <<= 1) {
        int u = (t >= off) ? sc[t - off] : 0;
        __syncthreads();
        sc[t] += u;
        __syncthreads();
    }
    if (i < N_NODES) rowstart[i] = sc[t] - v;   // exclusive within block
    if (t == 255) bsum[blockIdx.x] = sc[t];
}

__global__ void scan2_kernel(int* __restrict__ bsum) {
    __shared__ int sc[512];
    int t = threadIdx.x;
    int v = (t < SCAN_BLOCKS) ? bsum[t] : 0;
    sc[t] = v;
    __syncthreads();
    #pragma unroll
    for (int off = 1; off < 512; off <<= 1) {
        int u = (t >= off) ? sc[t - off] : 0;
        __syncthreads();
        sc[t] += u;
        __syncthreads();
    }
    if (t < SCAN_BLOCKS) bsum[t] = sc[t] - v;   // exclusive
}

// fill: pure scatter, no atomics, 4 independent stores/thread.
__global__ void fill_kernel(const int* __restrict__ ei,
                            const int* __restrict__ rowstart,
                            const int* __restrict__ bsum,
                            const int* __restrict__ pos,
                            int* __restrict__ csr) {
    int idx = blockIdx.x * blockDim.x + threadIdx.x;
    if (idx < N_EDGES / 4) {
        int4 s4 = ((const int4*)ei)[idx];
        int4 d4 = ((const int4*)(ei + N_EDGES))[idx];
        int4 p4 = ((const int4*)pos)[idx];
        int d;
        d = clampN(d4.x); csr[rowstart[d] + bsum[d >> 8] + p4.x] = clampN(s4.x);
        d = clampN(d4.y); csr[rowstart[d] + bsum[d >> 8] + p4.y] = clampN(s4.y);
        d = clampN(d4.z); csr[rowstart[d] + bsum[d >> 8] + p4.z] = clampN(s4.z);
        d = clampN(d4.w); csr[rowstart[d] + bsum[d >> 8] + p4.w] = clampN(s4.w);
    }
}

// ---------------------------------------------------------------------------
// convert: x (fp32) -> xb (bf16 rows, 128 B) ; last block builds wt[d][k] =
// bf16 of [Wl0 | Wr0] row-concat (64 rows x 128 k). Runs AFTER fill (xb
// aliases pos).
// ---------------------------------------------------------------------------
__global__ void convert_kernel(const float4* __restrict__ x4,
                               uint2* __restrict__ xb4,
                               const float* __restrict__ Wl0,
                               const float* __restrict__ Wr0,
                               short* __restrict__ wt) {
    if (blockIdx.x < 6250) {
        int idx = blockIdx.x * 256 + threadIdx.x;   // 1.6M float4s exactly
        float4 f = x4[idx];
        xb4[idx] = make_uint2(packbf2(f.x, f.y), packbf2(f.z, f.w));
    } else {
        for (int i = threadIdx.x; i < 8192; i += 256) {
            int d = i >> 7, k = i & 127;
            float v = (k < 64) ? Wl0[d * 64 + k] : Wr0[d * 64 + (k - 64)];
            wt[i] = f2bs(v);
        }
    }
}

// ---------------------------------------------------------------------------
// Aggregate: one wave per node; 4 quarter-waves (16 lanes x uint2 = 4 bf16
// dims) each own one edge row per issue, 2 accumulators => 8 row-gathers in
// flight; bf16 rows halve gather bytes vs fp32. Writes bf16 mean row.
// ---------------------------------------------------------------------------
__global__ void aggregate_kernel(const uint2* __restrict__ xb2,
                                 const int* __restrict__ rowstart,
                                 const int* __restrict__ bsum,
                                 const int* __restrict__ degi,
                                 const int* __restrict__ csr,
                                 uint2* __restrict__ mu2) {
    int tid = threadIdx.x;
    int q = (tid >> 4) & 3;
    int l16 = tid & 15;
    int n = blockIdx.x * 4 + (tid >> 6);
    if (n >= N_NODES) return;
    int beg = rowstart[n] + bsum[n >> 8];
    int cnt = degi[n];

    float4 a0 = make_float4(0.f, 0.f, 0.f, 0.f);
    float4 a1 = make_float4(0.f, 0.f, 0.f, 0.f);
    int i = 0;
    for (; i + 8 <= cnt; i += 8) {
        int s0 = csr[beg + i + q];
        int s1 = csr[beg + i + 4 + q];
        uint2 u0 = xb2[(long)s0 * 16 + l16];
        uint2 u1 = xb2[(long)s1 * 16 + l16];
        float2 fa = upk(u0.x), fb = upk(u0.y), fc = upk(u1.x), fd = upk(u1.y);
        a0.x += fa.x; a0.y += fa.y; a0.z += fb.x; a0.w += fb.y;
        a1.x += fc.x; a1.y += fc.y; a1.z += fd.x; a1.w += fd.y;
    }
    if (i + q < cnt) {
        uint2 u0 = xb2[(long)csr[beg + i + q] * 16 + l16];
        float2 fa = upk(u0.x), fb = upk(u0.y);
        a0.x += fa.x; a0.y += fa.y; a0.z += fb.x; a0.w += fb.y;
    }
    if (i + 4 + q < cnt) {
        uint2 u1 = xb2[(long)csr[beg + i + 4 + q] * 16 + l16];
        float2 fc = upk(u1.x), fd = upk(u1.y);
        a1.x += fc.x; a1.y += fc.y; a1.z += fd.x; a1.w += fd.y;
    }
    float4 a = make_float4(a0.x + a1.x, a0.y + a1.y, a0.z + a1.z, a0.w + a1.w);
    #pragma unroll
    for (int off = 16; off <= 32; off <<= 1) {
        a.x += __shfl_xor(a.x, off, 64);
        a.y += __shfl_xor(a.y, off, 64);
        a.z += __shfl_xor(a.z, off, 64);
        a.w += __shfl_xor(a.w, off, 64);
    }
    if (q == 0) {
        float inv = 1.0f / fmaxf((float)cnt, 1.0f);
        mu2[(long)n * 16 + l16] =
            make_uint2(packbf2(a.x * inv, a.y * inv), packbf2(a.z * inv, a.w * inv));
    }
}

// ---------------------------------------------------------------------------
// GEMM via MFMA, no LDS: per wave, M-tile of 16 nodes, N=64, K=128.
//   A = [mean | x] (bf16), frag layout A[m=lane&15][k=quad*8+j]
//   B = wt[n=d][k] rows (bf16, L1-resident 16 KB), frag B[k=quad*8+j][n=lane&15]
//   C/D: col(d)=lane&15, row(node)=quad*4+reg   [m89-verified]
// Epilogue: relu + s=h.Wl1, t=h.Wr1 via 16-lane shfl reduction.
// ---------------------------------------------------------------------------
__global__ __launch_bounds__(256) void gemm_mfma_kernel(
        const short* __restrict__ mu, const short* __restrict__ xb,
        const short* __restrict__ wt, const float* __restrict__ bl0,
        const float* __restrict__ Wl1, const float* __restrict__ Wr1,
        float* __restrict__ s, float* __restrict__ t) {
    const int lane = threadIdx.x & 63;
    const int wv = blockIdx.x * 4 + (threadIdx.x >> 6);
    const int m0 = wv * 16;
    if (m0 >= N_NODES) return;            // 100000 = 6250*16, no partial waves
    const int r = lane & 15;
    const int quad = lane >> 4;

    const long arow = (long)(m0 + r) * 64 + quad * 8;
    short8 a0 = *(const short8*)(mu + arow);        // k   0..31 (lane's 8)
    short8 a1 = *(const short8*)(mu + arow + 32);   // k  32..63
    short8 a2 = *(const short8*)(xb + arow);        // k  64..95
    short8 a3 = *(const short8*)(xb + arow + 32);   // k 96..127

    float hs[4] = {0.f, 0.f, 0.f, 0.f}, ht[4] = {0.f, 0.f, 0.f, 0.f};
    #pragma unroll
    for (int nt = 0; nt < 4; ++nt) {
        const int d = nt * 16 + r;
        const short* brow = wt + (long)d * 128 + quad * 8;
        short8 b0 = *(const short8*)(brow);
        short8 b1 = *(const short8*)(brow + 32);
        short8 b2 = *(const short8*)(brow + 64);
        short8 b3 = *(const short8*)(brow + 96);
        float bb = bl0[d];
        floatx4 acc = {bb, bb, bb, bb};
        acc = __builtin_amdgcn_mfma_f32_16x16x32_bf16(a0, b0, acc, 0, 0, 0);
        acc = __builtin_amdgcn_mfma_f32_16x16x32_bf16(a1, b1, acc, 0, 0, 0);
        acc = __builtin_amdgcn_mfma_f32_16x16x32_bf16(a2, b2, acc, 0, 0, 0);
        acc = __builtin_amdgcn_mfma_f32_16x16x32_bf16(a3, b3, acc, 0, 0, 0);
        float w1 = Wl1[d], w2 = Wr1[d];
        #pragma unroll
        for (int g = 0; g < 4; ++g) {
            float h = fmaxf(acc[g], 0.0f);
            hs[g] = fmaf(h, w1, hs[g]);
            ht[g] = fmaf(h, w2, ht[g]);
        }
    }
    #pragma unroll
    for (int g = 0; g < 4; ++g) {
        #pragma unroll
        for (int off = 1; off < 16; off <<= 1) {
            hs[g] += __shfl_xor(hs[g], off, 64);
            ht[g] += __shfl_xor(ht[g], off, 64);
        }
    }
    if (r == 0) {
        #pragma unroll
        for (int g = 0; g < 4; ++g) {
            s[m0 + quad * 4 + g] = hs[g];
            t[m0 + quad * 4 + g] = ht[g];
        }
    }
}

// ---------------------------------------------------------------------------
// Final: CSR-gather of s (4-wide ILP), mean, + bl1 + t, sigmoid, fp32 out.
// ---------------------------------------------------------------------------
__global__ void final_kernel(const float* __restrict__ s,
                             const float* __restrict__ t,
                             const int* __restrict__ rowstart,
                             const int* __restrict__ bsum,
                             const int* __restrict__ degi,
                             const int* __restrict__ csr,
                             const float* __restrict__ bl1,
                             float* __restrict__ out) {
    int n = blockIdx.x * 256 + threadIdx.x;
    if (n >= N_NODES) return;
    int beg = rowstart[n] + bsum[n >> 8];
    int cnt = degi[n];
    float acc = 0.0f;
    int i = 0;
    for (; i + 4 <= cnt; i += 4) {
        int e0 = csr[beg + i], e1 = csr[beg + i + 1];
        int e2 = csr[beg + i + 2], e3 = csr[beg + i + 3];
        acc += s[e0] + s[e1] + s[e2] + s[e3];
    }
    for (; i < cnt; ++i) acc += s[csr[beg + i]];
    float v = acc / fmaxf((float)cnt, 1.0f) + bl1[0] + t[n];
    float sg = 1.0f / (1.0f + expf(-v));
    out[n] = v;
    out[N_NODES + n] = sg;
}

extern "C" void kernel_launch(void* const* d_in, const int* in_sizes, int n_in,
                              void* d_out, int out_size, void* d_ws, size_t ws_size,
                              hipStream_t stream) {
    const float* x   = (const float*)d_in[0];
    const int*   ei  = (const int*)d_in[1];   // int32, [2,E] flat: src row, dst row
    const float* Wl0 = (const float*)d_in[2];
    const float* bl0 = (const float*)d_in[3];
    const float* Wr0 = (const float*)d_in[4];
    const float* Wl1 = (const float*)d_in[5];
    const float* bl1 = (const float*)d_in[6];
    const float* Wr1 = (const float*)d_in[7];
    float* out = (float*)d_out;

    // Workspace layout (31.2 MB). pos aliases xb (pos dead after fill;
    // convert overwrites xb after fill).
    //   degi     @0            (400,000)   zeroed
    //   rowstart @400,000      (400,000)
    //   bsum     @800,000      (4,096)
    //   s        @804,096      (400,000)
    //   t        @1,204,096    (400,000)
    //   csr      @1,604,096    (4,000,000)
    //   mu       @5,604,096    (12,800,000)   bf16 mean rows
    //   xb/pos   @18,404,096   (12,800,000)   bf16 x rows / int pos[1M]
    //   wt       @31,204,096   (16,384)       bf16 [Wl0|Wr0] rows
    char* ws = (char*)d_ws;
    int*   degi     = (int*)(ws);
    int*   rowstart = (int*)(ws + 400000);
    int*   bsum     = (int*)(ws + 800000);
    float* s        = (float*)(ws + 804096);
    float* t        = (float*)(ws + 1204096);
    int*   csr      = (int*)(ws + 1604096);
    unsigned int* mu = (unsigned int*)(ws + 5604096);
    char*  xb       = (ws + 18404096);
    int*   pos      = (int*)xb;
    short* wt       = (short*)(ws + 31204096);

    (void)hipMemsetAsync(degi, 0, 400000, stream);

    const int EB4 = (N_EDGES / 4 + 255) / 256;  // 977
    hist_kernel<<<EB4, 256, 0, stream>>>(ei, degi, pos);
    scan1_kernel<<<SCAN_BLOCKS, 256, 0, stream>>>(degi, rowstart, bsum);
    scan2_kernel<<<1, 512, 0, stream>>>(bsum);
    fill_kernel<<<EB4, 256, 0, stream>>>(ei, rowstart, bsum, pos, csr);
    convert_kernel<<<6251, 256, 0, stream>>>((const float4*)x, (uint2*)xb,
                                             Wl0, Wr0, wt);
    aggregate_kernel<<<25000, 256, 0, stream>>>((const uint2*)xb, rowstart,
                                                bsum, degi, csr, (uint2*)mu);
    gemm_mfma_kernel<<<1563, 256, 0, stream>>>((const short*)mu, (const short*)xb,
                                               wt, bl0, Wl1, Wr1, s, t);
    final_kernel<<<SCAN_BLOCKS, 256, 0, stream>>>(s, t, rowstart, bsum, degi, csr,
                                                  bl1, out);
}

// Round 10
// 201.244 us; speedup vs baseline: 3.0510x; 1.0913x over previous
//
#include <hip/hip_runtime.h>
#include <hip/hip_bf16.h>
#include <math.h>

#define N_NODES 100000
#define N_EDGES 1000000
#define DIM 64
#define SCAN_BLOCKS 391   // ceil(N_NODES/256)
#define AGPAD 72          // LDS row stride in shorts (16-B aligned, conflict-light)

// Device dtypes (established empirically R1-R8): fp32 floats, int32 indices,
// fp32 output.
typedef __hip_bfloat16 bf16;
typedef __attribute__((ext_vector_type(8))) short short8;
typedef __attribute__((ext_vector_type(4))) float floatx4;

__device__ __forceinline__ float b2f(bf16 v) { return __bfloat162float(v); }

__device__ __forceinline__ unsigned int packbf2(float a, float b) {
    bf16 x = __float2bfloat16(a), y = __float2bfloat16(b);
    unsigned short ux = *(unsigned short*)&x, uy = *(unsigned short*)&y;
    return (unsigned int)ux | ((unsigned int)uy << 16);
}

__device__ __forceinline__ short f2bs(float v) {
    bf16 x = __float2bfloat16(v);
    return *(short*)&x;
}

__device__ __forceinline__ float2 upk(unsigned int u) {
    unsigned short lo = (unsigned short)(u & 0xffff);
    unsigned short hi = (unsigned short)(u >> 16);
    bf16 a = *(bf16*)&lo, b = *(bf16*)&hi;
    return make_float2(b2f(a), b2f(b));
}

__device__ __forceinline__ int clampN(int v) {
    return v < 0 ? 0 : (v >= N_NODES ? N_NODES - 1 : v);
}

// ---------------------------------------------------------------------------
// Fused pre-pass, disjoint block ranges:
//   blocks [0,977)      : degree histogram + per-edge rank capture (pos)
//   blocks [977,7227)   : x fp32 -> xb bf16 rows (1.6M float4s exactly)
//   block  7227         : wt[d][k] = bf16 [Wl0 | Wr0] row-concat
// hist first: scan1 (next kernel) depends on it; convert consumed later.
// ---------------------------------------------------------------------------
__global__ void hist_convert_kernel(const int* __restrict__ ei,
                                    int* __restrict__ degi,
                                    int* __restrict__ pos,
                                    const float4* __restrict__ x4,
                                    uint2* __restrict__ xb4,
                                    const float* __restrict__ Wl0,
                                    const float* __restrict__ Wr0,
                                    short* __restrict__ wt) {
    int b = blockIdx.x;
    if (b < 977) {
        int idx = b * 256 + threadIdx.x;
        if (idx < N_EDGES / 4) {
            int4 d4 = ((const int4*)(ei + N_EDGES))[idx];
            int4 p;
            p.x = atomicAdd(&degi[clampN(d4.x)], 1);
            p.y = atomicAdd(&degi[clampN(d4.y)], 1);
            p.z = atomicAdd(&degi[clampN(d4.z)], 1);
            p.w = atomicAdd(&degi[clampN(d4.w)], 1);
            ((int4*)pos)[idx] = p;
        }
    } else if (b < 7227) {
        int idx = (b - 977) * 256 + threadIdx.x;   // < 1,600,000 exactly
        float4 f = x4[idx];
        xb4[idx] = make_uint2(packbf2(f.x, f.y), packbf2(f.z, f.w));
    } else {
        for (int i = threadIdx.x; i < 8192; i += 256) {
            int d = i >> 7, k = i & 127;
            float v = (k < 64) ? Wl0[d * 64 + k] : Wr0[d * 64 + (k - 64)];
            wt[i] = f2bs(v);
        }
    }
}

__global__ void scan1_kernel(const int* __restrict__ degi,
                             int* __restrict__ rowstart, int* __restrict__ bsum) {
    __shared__ int sc[256];
    int t = threadIdx.x;
    int i = blockIdx.x * 256 + t;
    int v = (i < N_NODES) ? degi[i] : 0;
    sc[t] = v;
    __syncthreads();
    #pragma unroll
    for (int off = 1; off < 256; off <<= 1) {
        int u = (t >= off) ? sc[t - off] : 0;
        __syncthreads();
        sc[t] += u;
        __syncthreads();
    }
    if (i < N_NODES) rowstart[i] = sc[t] - v;   // exclusive within block
    if (t == 255) bsum[blockIdx.x] = sc[t];
}

__global__ void scan2_kernel(int* __restrict__ bsum) {
    __shared__ int sc[512];
    int t = threadIdx.x;
    int v = (t < SCAN_BLOCKS) ? bsum[t] : 0;
    sc[t] = v;
    __syncthreads();
    #pragma unroll
    for (int off = 1; off < 512; off <<= 1) {
        int u = (t >= off) ? sc[t - off] : 0;
        __syncthreads();
        sc[t] += u;
        __syncthreads();
    }
    if (t < SCAN_BLOCKS) bsum[t] = sc[t] - v;   // exclusive
}

// fill: pure scatter, no atomics (pos carries each edge's rank from hist).
__global__ void fill_kernel(const int* __restrict__ ei,
                            const int* __restrict__ rowstart,
                            const int* __restrict__ bsum,
                            const int* __restrict__ pos,
                            int* __restrict__ csr) {
    int idx = blockIdx.x * blockDim.x + threadIdx.x;
    if (idx < N_EDGES / 4) {
        int4 s4 = ((const int4*)ei)[idx];
        int4 d4 = ((const int4*)(ei + N_EDGES))[idx];
        int4 p4 = ((const int4*)pos)[idx];
        int d;
        d = clampN(d4.x); csr[rowstart[d] + bsum[d >> 8] + p4.x] = clampN(s4.x);
        d = clampN(d4.y); csr[rowstart[d] + bsum[d >> 8] + p4.y] = clampN(s4.y);
        d = clampN(d4.z); csr[rowstart[d] + bsum[d >> 8] + p4.z] = clampN(s4.z);
        d = clampN(d4.w); csr[rowstart[d] + bsum[d >> 8] + p4.w] = clampN(s4.w);
    }
}

// ---------------------------------------------------------------------------
// Fused aggregate + GEMM + heads. Block = 256 threads = 16 nodes.
// Phase 1: 16-lane quarter-wave per node; lane owns 4 dims (uint2 = 4 bf16),
//   4 independent accumulators over the node's edge list (4 gathers in
//   flight), no cross-lane reduce; bf16 mean -> LDS As[16][AGPAD].
// Phase 2: wave w computes output dims d = w*16 + (lane&15) via 4x
//   mfma_f32_16x16x32_bf16 over K=128 = [mean | x]:
//   A-frag A[m=lane&15][k=quad*8+j] (mean from LDS, x from xb global);
//   B-frag = wt[d][k] rows; C/D: node = quad*4+reg, d = lane&15 (R9-verified).
//   Epilogue: relu, dual head dots, 16-lane shfl reduce over d, LDS-atomic
//   combine across the 4 waves. mu buffer eliminated entirely.
// ---------------------------------------------------------------------------
__global__ __launch_bounds__(256) void agg_gemm_kernel(
        const uint2* __restrict__ xb2, const short* __restrict__ xb,
        const short* __restrict__ wt,
        const int* __restrict__ rowstart, const int* __restrict__ bsum,
        const int* __restrict__ degi, const int* __restrict__ csr,
        const float* __restrict__ bl0, const float* __restrict__ Wl1,
        const float* __restrict__ Wr1,
        float* __restrict__ s, float* __restrict__ t) {
    __shared__ short As[16 * AGPAD];
    __shared__ float sRed[16], tRed[16];
    const int tid = threadIdx.x;
    const int nb = blockIdx.x * 16;          // 100000 = 6250*16, always full

    if (tid < 16) { sRed[tid] = 0.0f; tRed[tid] = 0.0f; }

    // ---- phase 1: aggregate ----
    {
        int qn = tid >> 4;     // node-local 0..15
        int l  = tid & 15;     // lane in quarter: dims 4l..4l+3
        int n = nb + qn;
        int beg = rowstart[n] + bsum[n >> 8];
        int cnt = degi[n];
        float4 A0 = make_float4(0.f, 0.f, 0.f, 0.f);
        float4 A1 = A0, A2 = A0, A3 = A0;
        int i = 0;
        for (; i + 4 <= cnt; i += 4) {
            int e0 = csr[beg + i],     e1 = csr[beg + i + 1];
            int e2 = csr[beg + i + 2], e3 = csr[beg + i + 3];
            uint2 u0 = xb2[(long)e0 * 16 + l];
            uint2 u1 = xb2[(long)e1 * 16 + l];
            uint2 u2 = xb2[(long)e2 * 16 + l];
            uint2 u3 = xb2[(long)e3 * 16 + l];
            float2 f; 
            f = upk(u0.x); A0.x += f.x; A0.y += f.y; f = upk(u0.y); A0.z += f.x; A0.w += f.y;
            f = upk(u1.x); A1.x += f.x; A1.y += f.y; f = upk(u1.y); A1.z += f.x; A1.w += f.y;
            f = upk(u2.x); A2.x += f.x; A2.y += f.y; f = upk(u2.y); A2.z += f.x; A2.w += f.y;
            f = upk(u3.x); A3.x += f.x; A3.y += f.y; f = upk(u3.y); A3.z += f.x; A3.w += f.y;
        }
        if (i < cnt) {
            uint2 u = xb2[(long)csr[beg + i] * 16 + l];
            float2 f = upk(u.x); A0.x += f.x; A0.y += f.y;
            f = upk(u.y); A0.z += f.x; A0.w += f.y;
        }
        if (i + 1 < cnt) {
            uint2 u = xb2[(long)csr[beg + i + 1] * 16 + l];
            float2 f = upk(u.x); A1.x += f.x; A1.y += f.y;
            f = upk(u.y); A1.z += f.x; A1.w += f.y;
        }
        if (i + 2 < cnt) {
            uint2 u = xb2[(long)csr[beg + i + 2] * 16 + l];
            float2 f = upk(u.x); A2.x += f.x; A2.y += f.y;
            f = upk(u.y); A2.z += f.x; A2.w += f.y;
        }
        float inv = 1.0f / fmaxf((float)cnt, 1.0f);
        float ax = (A0.x + A1.x + A2.x + A3.x) * inv;
        float ay = (A0.y + A1.y + A2.y + A3.y) * inv;
        float az = (A0.z + A1.z + A2.z + A3.z) * inv;
        float aw = (A0.w + A1.w + A2.w + A3.w) * inv;
        *(uint2*)&As[qn * AGPAD + 4 * l] =
            make_uint2(packbf2(ax, ay), packbf2(az, aw));
    }
    __syncthreads();

    // ---- phase 2: MFMA + heads ----
    const int lane = tid & 63;
    const int w = tid >> 6;
    const int r = lane & 15;
    const int quad = lane >> 4;

    short8 a0 = *(const short8*)&As[r * AGPAD + quad * 8];        // k  0..31
    short8 a1 = *(const short8*)&As[r * AGPAD + 32 + quad * 8];   // k 32..63
    const long xrow = (long)(nb + r) * 64 + quad * 8;
    short8 a2 = *(const short8*)(xb + xrow);                      // k 64..95
    short8 a3 = *(const short8*)(xb + xrow + 32);                 // k 96..127

    const int d = w * 16 + r;
    const short* brow = wt + (long)d * 128 + quad * 8;
    short8 b0 = *(const short8*)(brow);
    short8 b1 = *(const short8*)(brow + 32);
    short8 b2 = *(const short8*)(brow + 64);
    short8 b3 = *(const short8*)(brow + 96);

    float bb = bl0[d];
    floatx4 acc = {bb, bb, bb, bb};
    acc = __builtin_amdgcn_mfma_f32_16x16x32_bf16(a0, b0, acc, 0, 0, 0);
    acc = __builtin_amdgcn_mfma_f32_16x16x32_bf16(a1, b1, acc, 0, 0, 0);
    acc = __builtin_amdgcn_mfma_f32_16x16x32_bf16(a2, b2, acc, 0, 0, 0);
    acc = __builtin_amdgcn_mfma_f32_16x16x32_bf16(a3, b3, acc, 0, 0, 0);

    float w1 = Wl1[d], w2 = Wr1[d];
    float hs[4], ht[4];
    #pragma unroll
    for (int g = 0; g < 4; ++g) {
        float h = fmaxf(acc[g], 0.0f);
        hs[g] = h * w1;
        ht[g] = h * w2;
    }
    #pragma unroll
    for (int g = 0; g < 4; ++g) {
        #pragma unroll
        for (int off = 1; off < 16; off <<= 1) {
            hs[g] += __shfl_xor(hs[g], off, 64);
            ht[g] += __shfl_xor(ht[g], off, 64);
        }
    }
    if (r == 0) {
        #pragma unroll
        for (int g = 0; g < 4; ++g) {
            atomicAdd(&sRed[quad * 4 + g], hs[g]);
            atomicAdd(&tRed[quad * 4 + g], ht[g]);
        }
    }
    __syncthreads();
    if (tid < 16) {
        s[nb + tid] = sRed[tid];
        t[nb + tid] = tRed[tid];
    }
}

// ---------------------------------------------------------------------------
// Final: CSR-gather of s (4-wide ILP), mean, + bl1 + t, sigmoid, fp32 out.
// ---------------------------------------------------------------------------
__global__ void final_kernel(const float* __restrict__ s,
                             const float* __restrict__ t,
                             const int* __restrict__ rowstart,
                             const int* __restrict__ bsum,
                             const int* __restrict__ degi,
                             const int* __restrict__ csr,
                             const float* __restrict__ bl1,
                             float* __restrict__ out) {
    int n = blockIdx.x * 256 + threadIdx.x;
    if (n >= N_NODES) return;
    int beg = rowstart[n] + bsum[n >> 8];
    int cnt = degi[n];
    float acc = 0.0f;
    int i = 0;
    for (; i + 4 <= cnt; i += 4) {
        int e0 = csr[beg + i], e1 = csr[beg + i + 1];
        int e2 = csr[beg + i + 2], e3 = csr[beg + i + 3];
        acc += s[e0] + s[e1] + s[e2] + s[e3];
    }
    for (; i < cnt; ++i) acc += s[csr[beg + i]];
    float v = acc / fmaxf((float)cnt, 1.0f) + bl1[0] + t[n];
    float sg = 1.0f / (1.0f + expf(-v));
    out[n] = v;
    out[N_NODES + n] = sg;
}

extern "C" void kernel_launch(void* const* d_in, const int* in_sizes, int n_in,
                              void* d_out, int out_size, void* d_ws, size_t ws_size,
                              hipStream_t stream) {
    const float* x   = (const float*)d_in[0];
    const int*   ei  = (const int*)d_in[1];   // int32, [2,E] flat: src row, dst row
    const float* Wl0 = (const float*)d_in[2];
    const float* bl0 = (const float*)d_in[3];
    const float* Wr0 = (const float*)d_in[4];
    const float* Wl1 = (const float*)d_in[5];
    const float* bl1 = (const float*)d_in[6];
    const float* Wr1 = (const float*)d_in[7];
    float* out = (float*)d_out;

    // Workspace layout (~22.4 MB, all offsets 16-B aligned):
    //   degi     @0            (400,000)   zeroed
    //   rowstart @400,000      (400,000)
    //   bsum     @800,000      (4,096)
    //   s        @804,096      (400,000)
    //   t        @1,204,096    (400,000)
    //   csr      @1,604,096    (4,000,000)
    //   pos      @5,604,096    (4,000,000)
    //   xb       @9,604,096    (12,800,000)  bf16 x rows
    //   wt       @22,404,096   (16,384)      bf16 [Wl0|Wr0] rows
    char* ws = (char*)d_ws;
    int*   degi     = (int*)(ws);
    int*   rowstart = (int*)(ws + 400000);
    int*   bsum     = (int*)(ws + 800000);
    float* s        = (float*)(ws + 804096);
    float* t        = (float*)(ws + 1204096);
    int*   csr      = (int*)(ws + 1604096);
    int*   pos      = (int*)(ws + 5604096);
    char*  xb       = (ws + 9604096);
    short* wt       = (short*)(ws + 22404096);

    (void)hipMemsetAsync(degi, 0, 400000, stream);

    hist_convert_kernel<<<7228, 256, 0, stream>>>(ei, degi, pos,
                                                  (const float4*)x, (uint2*)xb,
                                                  Wl0, Wr0, wt);
    scan1_kernel<<<SCAN_BLOCKS, 256, 0, stream>>>(degi, rowstart, bsum);
    scan2_kernel<<<1, 512, 0, stream>>>(bsum);
    fill_kernel<<<977, 256, 0, stream>>>(ei, rowstart, bsum, pos, csr);
    agg_gemm_kernel<<<6250, 256, 0, stream>>>((const uint2*)xb, (const short*)xb,
                                              wt, rowstart, bsum, degi, csr,
                                              bl0, Wl1, Wr1, s, t);
    final_kernel<<<SCAN_BLOCKS, 256, 0, stream>>>(s, t, rowstart, bsum, degi, csr,
                                                  bl1, out);
}